// Round 2
// baseline (3743.205 us; speedup 1.0000x reference)
//
#include <hip/hip_runtime.h>

#define BSZ 8
#define TLEN 2048
#define CDIM 768

// ---------------------------------------------------------------------------
// NT SGEMM: out[m,n] = sum_k A[m,k] * W[n,k]   (A: MxK row-major, W: NxK row-major)
// mode 0: plain; mode 1: sigmoid applied to output.
// 64x64 tile, BK=16, 256 threads, 4x4 accum per thread.
// ---------------------------------------------------------------------------
__global__ __launch_bounds__(256) void gemm_nt(const float* __restrict__ A,
                                               const float* __restrict__ W,
                                               float* __restrict__ out,
                                               int M, int N, int K, int mode) {
    __shared__ float As[16][68];
    __shared__ float Ws[16][68];

    const int tid = threadIdx.x;
    const int tx = tid & 15;        // 0..15 -> n
    const int ty = tid >> 4;        // 0..15 -> m
    const int m0 = blockIdx.y * 64;
    const int n0 = blockIdx.x * 64;

    const int lrow = tid >> 2;      // 0..63
    const int lk   = (tid & 3) * 4; // 0,4,8,12

    const float* Arow = A + (size_t)(m0 + lrow) * K + lk;
    const float* Wrow = W + (size_t)(n0 + lrow) * K + lk;

    float acc[4][4] = {};

    for (int k0 = 0; k0 < K; k0 += 16) {
        float4 av = *(const float4*)(Arow + k0);
        float4 wv = *(const float4*)(Wrow + k0);
        As[lk + 0][lrow] = av.x; As[lk + 1][lrow] = av.y;
        As[lk + 2][lrow] = av.z; As[lk + 3][lrow] = av.w;
        Ws[lk + 0][lrow] = wv.x; Ws[lk + 1][lrow] = wv.y;
        Ws[lk + 2][lrow] = wv.z; Ws[lk + 3][lrow] = wv.w;
        __syncthreads();

        #pragma unroll
        for (int kk = 0; kk < 16; ++kk) {
            float a[4], b[4];
            #pragma unroll
            for (int i = 0; i < 4; ++i) a[i] = As[kk][ty * 4 + i];
            #pragma unroll
            for (int j = 0; j < 4; ++j) b[j] = Ws[kk][tx * 4 + j];
            #pragma unroll
            for (int i = 0; i < 4; ++i)
                #pragma unroll
                for (int j = 0; j < 4; ++j)
                    acc[i][j] = fmaf(a[i], b[j], acc[i][j]);
        }
        __syncthreads();
    }

    #pragma unroll
    for (int i = 0; i < 4; ++i) {
        const int m = m0 + ty * 4 + i;
        #pragma unroll
        for (int j = 0; j < 4; ++j) {
            const int n = n0 + tx * 4 + j;
            float vo = acc[i][j];
            if (mode == 1) vo = 1.0f / (1.0f + __expf(-vo));
            out[(size_t)m * N + n] = vo;
        }
    }
}

// ---------------------------------------------------------------------------
// WKV backward scan over a chunk of `curb` batches: for each (b,c), iterate
// t = T-1..0, emitting the pre-update state (covers indices > t) at [b,t,c].
// ---------------------------------------------------------------------------
__global__ __launch_bounds__(64) void wkv_backward(const float* __restrict__ k,
                                                   const float* __restrict__ v,
                                                   const float* __restrict__ decay,
                                                   float* __restrict__ aR,
                                                   float* __restrict__ bR,
                                                   float* __restrict__ pR,
                                                   int curb) {
    const int idx = blockIdx.x * blockDim.x + threadIdx.x; // blocal*C + c
    if (idx >= curb * CDIM) return;
    const int c = idx % CDIM;
    const float w = decay[c] * (1.0f / (float)TLEN);

    const size_t base = (size_t)(idx / CDIM) * TLEN * CDIM + c;
    float a = 0.0f, bb = 0.0f, p = -1e38f;

    for (int t = TLEN - 1; t >= 0; --t) {
        const size_t off = base + (size_t)t * CDIM;
        aR[off] = a; bR[off] = bb; pR[off] = p;
        const float kt = k[off];
        const float vt = v[off];
        const float pn = fmaxf(p - w, kt);
        const float e1 = __expf(p - w - pn);
        const float e2 = __expf(kt - pn);
        a  = e1 * a  + e2 * vt;
        bb = e1 * bb + e2;
        p  = pn;
    }
}

// ---------------------------------------------------------------------------
// WKV forward scan + combine: left state computed on the fly; right state read
// from aR/bR/pR; z = sr * y written (z aliases aR: read-before-write, same
// thread, same index).
// ---------------------------------------------------------------------------
__global__ __launch_bounds__(64) void wkv_forward(const float* k,
                                                  const float* v,
                                                  const float* sr,
                                                  const float* aR,
                                                  const float* bR,
                                                  const float* pR,
                                                  const float* decay,
                                                  const float* first,
                                                  float* z, int curb) {
    const int idx = blockIdx.x * blockDim.x + threadIdx.x; // blocal*C + c
    if (idx >= curb * CDIM) return;
    const int c = idx % CDIM;
    const float w = decay[c] * (1.0f / (float)TLEN);
    const float u = first[c] * (1.0f / (float)TLEN);

    const size_t base = (size_t)(idx / CDIM) * TLEN * CDIM + c;
    float a = 0.0f, bb = 0.0f, p = -1e38f;

    for (int t = 0; t < TLEN; ++t) {
        const size_t off = base + (size_t)t * CDIM;
        const float kt = k[off];
        const float vt = v[off];
        const float ar = aR[off];
        const float br = bR[off];
        const float pr = pR[off];
        const float srt = sr[off];

        const float ps = u + kt;
        const float q  = fmaxf(fmaxf(p, pr), ps);
        const float eL = __expf(p - q);
        const float eR = __expf(pr - q);
        const float eS = __expf(ps - q);
        const float num = eL * a  + eR * ar + eS * vt;
        const float den = eL * bb + eR * br + eS;
        const float y = num / den;
        z[off] = srt * y;

        const float pn = fmaxf(p - w, kt);
        const float e1 = __expf(p - w - pn);
        const float e2 = __expf(kt - pn);
        a  = e1 * a  + e2 * vt;
        bb = e1 * bb + e2;
        p  = pn;
    }
}

// ---------------------------------------------------------------------------
// Batch-chunked driver: per-batch scratch footprint is 6 * T*C * 4B = 37.75 MB.
// Chunk size nb = how many batches fit in ws_size (capped at BSZ).
// ---------------------------------------------------------------------------
extern "C" void kernel_launch(void* const* d_in, const int* in_sizes, int n_in,
                              void* d_out, int out_size, void* d_ws, size_t ws_size,
                              hipStream_t stream) {
    const float* x     = (const float*)d_in[0];
    const float* Wk    = (const float*)d_in[1];
    const float* Wv    = (const float*)d_in[2];
    const float* Wr    = (const float*)d_in[3];
    const float* Wo    = (const float*)d_in[4];
    const float* decay = (const float*)d_in[5];
    const float* first = (const float*)d_in[6];
    float* out = (float*)d_out;

    const size_t per_b = 6ull * TLEN * CDIM * sizeof(float); // 37,748,736 B
    int nb = (int)(ws_size / per_b);
    if (nb < 1) return;           // cannot run without >= 38 MB scratch
    if (nb > BSZ) nb = BSZ;

    const size_t NE = (size_t)nb * TLEN * CDIM; // chunk array stride (elements)
    float* k  = (float*)d_ws;
    float* v  = k + NE;
    float* sr = v + NE;
    float* aR = sr + NE;
    float* bR = aR + NE;
    float* pR = bR + NE;
    float* z  = aR; // alias: forward kernel reads aR[t] before writing z[t]

    for (int b0 = 0; b0 < BSZ; b0 += nb) {
        const int curb = (BSZ - b0 < nb) ? (BSZ - b0) : nb;
        const int rows = curb * TLEN;
        const float* xc  = x   + (size_t)b0 * TLEN * CDIM;
        float*       oc  = out + (size_t)b0 * TLEN * CDIM;

        dim3 blk(256);
        dim3 grid(CDIM / 64, rows / 64);

        gemm_nt<<<grid, blk, 0, stream>>>(xc, Wk, k,  rows, CDIM, CDIM, 0);
        gemm_nt<<<grid, blk, 0, stream>>>(xc, Wv, v,  rows, CDIM, CDIM, 0);
        gemm_nt<<<grid, blk, 0, stream>>>(xc, Wr, sr, rows, CDIM, CDIM, 1);

        const int nch = curb * CDIM;
        wkv_backward<<<dim3((nch + 63) / 64), dim3(64), 0, stream>>>(
            k, v, decay, aR, bR, pR, curb);
        wkv_forward <<<dim3((nch + 63) / 64), dim3(64), 0, stream>>>(
            k, v, sr, aR, bR, pR, decay, first, z, curb);

        gemm_nt<<<grid, blk, 0, stream>>>(z, Wo, oc, rows, CDIM, CDIM, 0);
    }
}

// Round 3
// 1128.697 us; speedup vs baseline: 3.3164x; 3.3164x over previous
//
#include <hip/hip_runtime.h>

#define BSZ 8
#define TLEN 2048
#define CDIM 768
#define LCH 16                 // within-chunk length (registers, fully unrolled)
#define NCH (TLEN / LCH)       // 128 chunks

// ---------------------------------------------------------------------------
// NT SGEMM: out[m,n] = sum_k A[m,k] * W[n,k]; mode 1 applies sigmoid.
// ---------------------------------------------------------------------------
__global__ __launch_bounds__(256) void gemm_nt(const float* __restrict__ A,
                                               const float* __restrict__ W,
                                               float* __restrict__ out,
                                               int M, int N, int K, int mode) {
    __shared__ float As[16][68];
    __shared__ float Ws[16][68];

    const int tid = threadIdx.x;
    const int tx = tid & 15;
    const int ty = tid >> 4;
    const int m0 = blockIdx.y * 64;
    const int n0 = blockIdx.x * 64;

    const int lrow = tid >> 2;
    const int lk   = (tid & 3) * 4;

    const float* Arow = A + (size_t)(m0 + lrow) * K + lk;
    const float* Wrow = W + (size_t)(n0 + lrow) * K + lk;

    float acc[4][4] = {};

    for (int k0 = 0; k0 < K; k0 += 16) {
        float4 av = *(const float4*)(Arow + k0);
        float4 wv = *(const float4*)(Wrow + k0);
        As[lk + 0][lrow] = av.x; As[lk + 1][lrow] = av.y;
        As[lk + 2][lrow] = av.z; As[lk + 3][lrow] = av.w;
        Ws[lk + 0][lrow] = wv.x; Ws[lk + 1][lrow] = wv.y;
        Ws[lk + 2][lrow] = wv.z; Ws[lk + 3][lrow] = wv.w;
        __syncthreads();

        #pragma unroll
        for (int kk = 0; kk < 16; ++kk) {
            float a[4], b[4];
            #pragma unroll
            for (int i = 0; i < 4; ++i) a[i] = As[kk][ty * 4 + i];
            #pragma unroll
            for (int j = 0; j < 4; ++j) b[j] = Ws[kk][tx * 4 + j];
            #pragma unroll
            for (int i = 0; i < 4; ++i)
                #pragma unroll
                for (int j = 0; j < 4; ++j)
                    acc[i][j] = fmaf(a[i], b[j], acc[i][j]);
        }
        __syncthreads();
    }

    #pragma unroll
    for (int i = 0; i < 4; ++i) {
        const int m = m0 + ty * 4 + i;
        #pragma unroll
        for (int j = 0; j < 4; ++j) {
            const int n = n0 + tx * 4 + j;
            float vo = acc[i][j];
            if (mode == 1) vo = 1.0f / (1.0f + __expf(-vo));
            out[(size_t)m * N + n] = vo;
        }
    }
}

// scan update: (a,b,p) <- step with (kt,vt), decay w
#define WKV_STEP(a, bb, p, kt, vt, w)                \
    {                                                \
        const float pn = fmaxf((p) - (w), (kt));     \
        const float e1 = __expf((p) - (w) - pn);     \
        const float e2 = __expf((kt) - pn);          \
        (a)  = e1 * (a)  + e2 * (vt);                \
        (bb) = e1 * (bb) + e2;                       \
        (p)  = pn;                                   \
    }

// ---------------------------------------------------------------------------
// Phase 1: per (b, chunk j, c) compute stabilized chunk summaries for both
// scan directions. Summary (a,b,p): S_A = a*e^p over the chunk's items.
// ---------------------------------------------------------------------------
__global__ __launch_bounds__(256) void wkv_phase1(
    const float* __restrict__ k, const float* __restrict__ v,
    const float* __restrict__ decay,
    float* __restrict__ Sfa, float* __restrict__ Sfb, float* __restrict__ Sfp,
    float* __restrict__ Sba, float* __restrict__ Sbb, float* __restrict__ Sbp) {
    const int c = blockIdx.x * 256 + threadIdx.x;
    const int j = blockIdx.y;
    const int b = blockIdx.z;
    const float w = decay[c] * (1.0f / (float)TLEN);

    const size_t base = ((size_t)b * TLEN + (size_t)j * LCH) * CDIM + c;
    float kt[LCH], vt[LCH];
    #pragma unroll
    for (int i = 0; i < LCH; ++i) {
        kt[i] = k[base + (size_t)i * CDIM];
        vt[i] = v[base + (size_t)i * CDIM];
    }

    const size_t idx = ((size_t)b * NCH + j) * CDIM + c;

    float a = 0.0f, bb = 0.0f, p = -1e38f;
    #pragma unroll
    for (int i = 0; i < LCH; ++i) WKV_STEP(a, bb, p, kt[i], vt[i], w);
    Sfa[idx] = a; Sfb[idx] = bb; Sfp[idx] = p;

    a = 0.0f; bb = 0.0f; p = -1e38f;
    #pragma unroll
    for (int i = LCH - 1; i >= 0; --i) WKV_STEP(a, bb, p, kt[i], vt[i], w);
    Sba[idx] = a; Sbb[idx] = bb; Sbp[idx] = p;
}

// combine: state X absorbs chunk summary S after decaying by wL (L steps)
#define WKV_COMBINE(a, bb, p, as, bs, ps, wL)        \
    {                                                \
        const float pn = fmaxf((p) - (wL), (ps));    \
        const float e1 = __expf((p) - (wL) - pn);    \
        const float e2 = __expf((ps) - pn);          \
        (a)  = e1 * (a)  + e2 * (as);                \
        (bb) = e1 * (bb) + e2 * (bs);                \
        (p)  = pn;                                   \
    }

// ---------------------------------------------------------------------------
// Phase 2: per (b,c) scan over chunk summaries in both directions, emitting
// the pre-combine (incoming) state per chunk.
// ---------------------------------------------------------------------------
__global__ __launch_bounds__(64) void wkv_phase2(
    const float* __restrict__ Sfa, const float* __restrict__ Sfb, const float* __restrict__ Sfp,
    const float* __restrict__ Sba, const float* __restrict__ Sbb, const float* __restrict__ Sbp,
    const float* __restrict__ decay,
    float* __restrict__ Lina, float* __restrict__ Linb, float* __restrict__ Linp,
    float* __restrict__ Rina, float* __restrict__ Rinb, float* __restrict__ Rinp) {
    const int c = blockIdx.x * 64 + threadIdx.x;
    const int b = blockIdx.y;
    const float wL = decay[c] * ((float)LCH / (float)TLEN);

    // forward direction
    {
        float a = 0.0f, bb = 0.0f, p = -1e38f;
        for (int j = 0; j < NCH; ++j) {
            const size_t idx = ((size_t)b * NCH + j) * CDIM + c;
            Lina[idx] = a; Linb[idx] = bb; Linp[idx] = p;
            WKV_COMBINE(a, bb, p, Sfa[idx], Sfb[idx], Sfp[idx], wL);
        }
    }
    // backward direction
    {
        float a = 0.0f, bb = 0.0f, p = -1e38f;
        for (int j = NCH - 1; j >= 0; --j) {
            const size_t idx = ((size_t)b * NCH + j) * CDIM + c;
            Rina[idx] = a; Rinb[idx] = bb; Rinp[idx] = p;
            WKV_COMBINE(a, bb, p, Sba[idx], Sbb[idx], Sbp[idx], wL);
        }
    }
}

// ---------------------------------------------------------------------------
// Phase 3: per (b, chunk j, c): backward pass within chunk from incoming right
// state (per-position states kept in registers), then forward pass from
// incoming left state, combining + fusing z = sr * y. z may alias sr.
// ---------------------------------------------------------------------------
__global__ __launch_bounds__(256) void wkv_phase3(
    const float* __restrict__ k, const float* __restrict__ v,
    const float* __restrict__ sr,
    const float* __restrict__ Lina, const float* __restrict__ Linb, const float* __restrict__ Linp,
    const float* __restrict__ Rina, const float* __restrict__ Rinb, const float* __restrict__ Rinp,
    const float* __restrict__ decay, const float* __restrict__ first,
    float* __restrict__ z) {
    const int c = blockIdx.x * 256 + threadIdx.x;
    const int j = blockIdx.y;
    const int b = blockIdx.z;
    const float w = decay[c] * (1.0f / (float)TLEN);
    const float u = first[c] * (1.0f / (float)TLEN);

    const size_t base = ((size_t)b * TLEN + (size_t)j * LCH) * CDIM + c;
    float kt[LCH], vt[LCH];
    #pragma unroll
    for (int i = 0; i < LCH; ++i) {
        kt[i] = k[base + (size_t)i * CDIM];
        vt[i] = v[base + (size_t)i * CDIM];
    }

    const size_t idx = ((size_t)b * NCH + j) * CDIM + c;

    // pass A: backward within chunk; record pre-update (covers all t' > t)
    float ar[LCH], br[LCH], pr[LCH];
    {
        float a = Rina[idx], bb = Rinb[idx], p = Rinp[idx];
        #pragma unroll
        for (int i = LCH - 1; i >= 0; --i) {
            ar[i] = a; br[i] = bb; pr[i] = p;
            WKV_STEP(a, bb, p, kt[i], vt[i], w);
        }
    }

    // pass B: forward within chunk; combine and emit
    {
        float a = Lina[idx], bb = Linb[idx], p = Linp[idx];
        #pragma unroll
        for (int i = 0; i < LCH; ++i) {
            const float srt = sr[base + (size_t)i * CDIM];
            const float ps = u + kt[i];
            const float q  = fmaxf(fmaxf(p, pr[i]), ps);
            const float eL = __expf(p - q);
            const float eR = __expf(pr[i] - q);
            const float eS = __expf(ps - q);
            const float num = eL * a  + eR * ar[i] + eS * vt[i];
            const float den = eL * bb + eR * br[i] + eS;
            z[base + (size_t)i * CDIM] = srt * (num / den);
            WKV_STEP(a, bb, p, kt[i], vt[i], w);
        }
    }
}

// ---------------------------------------------------------------------------
// Driver. Per-batch scratch: 3*T*C floats (k,v,sr) + 12*NCH*C floats (states)
// = 23.6 MB. Batch-chunked to fit ws_size.
// ---------------------------------------------------------------------------
extern "C" void kernel_launch(void* const* d_in, const int* in_sizes, int n_in,
                              void* d_out, int out_size, void* d_ws, size_t ws_size,
                              hipStream_t stream) {
    const float* x     = (const float*)d_in[0];
    const float* Wk    = (const float*)d_in[1];
    const float* Wv    = (const float*)d_in[2];
    const float* Wr    = (const float*)d_in[3];
    const float* Wo    = (const float*)d_in[4];
    const float* decay = (const float*)d_in[5];
    const float* first = (const float*)d_in[6];
    float* out = (float*)d_out;

    const size_t per_b = (3ull * TLEN * CDIM + 12ull * NCH * CDIM) * sizeof(float);
    int nb = (int)(ws_size / per_b);
    if (nb < 1) return;
    if (nb > BSZ) nb = BSZ;

    const size_t NE = (size_t)nb * TLEN * CDIM;   // big array stride (elements)
    const size_t NP = (size_t)nb * NCH * CDIM;    // state plane stride
    float* k    = (float*)d_ws;
    float* v    = k + NE;
    float* sr   = v + NE;
    float* Sfa  = sr + NE;
    float* Sfb  = Sfa + NP;
    float* Sfp  = Sfb + NP;
    float* Sba  = Sfp + NP;
    float* Sbb  = Sba + NP;
    float* Sbp  = Sbb + NP;
    float* Lina = Sbp + NP;
    float* Linb = Lina + NP;
    float* Linp = Linb + NP;
    float* Rina = Linp + NP;
    float* Rinb = Rina + NP;
    float* Rinp = Rinb + NP;
    float* z    = sr;   // alias: phase3 reads sr[i] before writing z[i], same thread

    for (int b0 = 0; b0 < BSZ; b0 += nb) {
        const int curb = (BSZ - b0 < nb) ? (BSZ - b0) : nb;
        const int rows = curb * TLEN;
        const float* xc = x   + (size_t)b0 * TLEN * CDIM;
        float*       oc = out + (size_t)b0 * TLEN * CDIM;

        dim3 gblk(256);
        dim3 ggrid(CDIM / 64, rows / 64);
        gemm_nt<<<ggrid, gblk, 0, stream>>>(xc, Wk, k,  rows, CDIM, CDIM, 0);
        gemm_nt<<<ggrid, gblk, 0, stream>>>(xc, Wv, v,  rows, CDIM, CDIM, 0);
        gemm_nt<<<ggrid, gblk, 0, stream>>>(xc, Wr, sr, rows, CDIM, CDIM, 1);

        wkv_phase1<<<dim3(CDIM / 256, NCH, curb), dim3(256), 0, stream>>>(
            k, v, decay, Sfa, Sfb, Sfp, Sba, Sbb, Sbp);
        wkv_phase2<<<dim3(CDIM / 64, curb), dim3(64), 0, stream>>>(
            Sfa, Sfb, Sfp, Sba, Sbb, Sbp, decay,
            Lina, Linb, Linp, Rina, Rinb, Rinp);
        wkv_phase3<<<dim3(CDIM / 256, NCH, curb), dim3(256), 0, stream>>>(
            k, v, sr, Lina, Linb, Linp, Rina, Rinb, Rinp, decay, first, z);

        gemm_nt<<<ggrid, gblk, 0, stream>>>(z, Wo, oc, rows, CDIM, CDIM, 0);
    }
}

// Round 4
// 470.244 us; speedup vs baseline: 7.9601x; 2.4002x over previous
//
#include <hip/hip_runtime.h>

#define BSZ 8
#define TLEN 2048
#define CDIM 768
#define LCH 16
#define NCH (TLEN / LCH)

typedef __attribute__((ext_vector_type(4))) float f32x4;
typedef __attribute__((ext_vector_type(8))) short bf16x8;   // 8 bf16 in 4 VGPRs (MFMA operand)
typedef __attribute__((ext_vector_type(4))) int int4v;
typedef __attribute__((ext_vector_type(4))) unsigned short us4;
typedef __attribute__((ext_vector_type(4))) float float4v;

__device__ __forceinline__ unsigned short f2bf(float f) {
    unsigned int u = __float_as_uint(f);
    u += 0x7fffu + ((u >> 16) & 1u);   // RNE
    return (unsigned short)(u >> 16);
}
__device__ __forceinline__ float bf2f(unsigned short h) {
    return __uint_as_float(((unsigned int)h) << 16);
}

// ---------------------------------------------------------------------------
// split f32 -> (hi, lo) bf16, 4 elements/thread. n4 = n/4.
// ---------------------------------------------------------------------------
__global__ __launch_bounds__(256) void split_f32(const float* __restrict__ src,
                                                 unsigned short* __restrict__ hi,
                                                 unsigned short* __restrict__ lo,
                                                 int n4) {
    int i = blockIdx.x * 256 + threadIdx.x;
    if (i >= n4) return;
    float4v f = ((const float4v*)src)[i];
    us4 h, l;
    #pragma unroll
    for (int j = 0; j < 4; ++j) {
        unsigned short hh = f2bf(f[j]);
        h[j] = hh;
        l[j] = f2bf(f[j] - bf2f(hh));
    }
    ((us4*)hi)[i] = h;
    ((us4*)lo)[i] = l;
}

// ---------------------------------------------------------------------------
// Split-precision MFMA GEMM (NT): out[m,n] = sum_k A[m,k]*W[n,k], A=Ah+Al,
// W=Wh+Wl (bf16), fp32 accum via 3 MFMAs (hh, hl, lh). N=K=CDIM.
// 128x128 tile, BK=32, 256 thr (4 waves, 2x2 wave grid), 16x16x32 bf16 MFMA.
// LDS [128][32] bf16 per tile, XOR swizzle kg ^= (row>>3)&1 on write+read.
// mode 1: sigmoid epilogue.
// ---------------------------------------------------------------------------
__global__ __launch_bounds__(256) void gemm_mfma_split(
    const unsigned short* __restrict__ Ah, const unsigned short* __restrict__ Al,
    const unsigned short* __restrict__ Wh, const unsigned short* __restrict__ Wl,
    float* __restrict__ out, int mode) {
    constexpr int K = CDIM, N = CDIM;
    __shared__ __align__(16) char smem[2][4][8192];  // [buf][Ah,Al,Wh,Wl][128*32*2B]

    const int tid  = threadIdx.x;
    const int lane = tid & 63;
    const int wid  = tid >> 6;
    const int m0 = blockIdx.y * 128;
    const int n0 = blockIdx.x * 128;

    // staging: wave `wid` owns tile `wid` (0=Ah,1=Al,2=Wh,3=Wl)
    const unsigned short* gsrc = (wid == 0) ? Ah : (wid == 1) ? Al : (wid == 2) ? Wh : Wl;
    const int rbase_g = (wid < 2) ? m0 : n0;

    int4v regs[8];
    auto LOAD = [&](int k0) {
        #pragma unroll
        for (int q = 0; q < 8; ++q) {
            const int j = q * 64 + lane;       // 16B-segment index in tile
            const int row = j >> 2, kgp = j & 3;
            regs[q] = *(const int4v*)(gsrc + (size_t)(rbase_g + row) * K + k0 + kgp * 8);
        }
    };
    auto STORE = [&](int buf) {
        char* base = &smem[buf][wid][0];
        #pragma unroll
        for (int q = 0; q < 8; ++q) {
            const int j = q * 64 + lane;
            const int row = j >> 2, kgp = j & 3;
            const int kw = kgp ^ ((row >> 3) & 1);
            *(int4v*)(base + row * 64 + kw * 16) = regs[q];
        }
    };

    const int wr = wid >> 1, wc = wid & 1;
    f32x4 acc[4][4];
    #pragma unroll
    for (int i = 0; i < 4; ++i)
        #pragma unroll
        for (int j = 0; j < 4; ++j)
            acc[i][j] = (f32x4){0.f, 0.f, 0.f, 0.f};

    // fragment read: row = tilebase + fi*16 + (lane&15), kgroup = lane>>4 (swizzled)
    const int kx = (((lane >> 4) ^ ((lane >> 3) & 1)) << 4);  // swizzled byte offset of k-group
    const int ra = wr * 64 + (lane & 15);
    const int rb = wc * 64 + (lane & 15);

    auto COMPUTE = [&](int buf) {
        const char* sAh = &smem[buf][0][0];
        const char* sAl = &smem[buf][1][0];
        const char* sWh = &smem[buf][2][0];
        const char* sWl = &smem[buf][3][0];
        bf16x8 ah[4], al[4], bh[4], bl[4];
        #pragma unroll
        for (int i = 0; i < 4; ++i) {
            ah[i] = *(const bf16x8*)(sAh + (ra + i * 16) * 64 + kx);
            al[i] = *(const bf16x8*)(sAl + (ra + i * 16) * 64 + kx);
            bh[i] = *(const bf16x8*)(sWh + (rb + i * 16) * 64 + kx);
            bl[i] = *(const bf16x8*)(sWl + (rb + i * 16) * 64 + kx);
        }
        #pragma unroll
        for (int i = 0; i < 4; ++i)
            #pragma unroll
            for (int j = 0; j < 4; ++j) {
                acc[i][j] = __builtin_amdgcn_mfma_f32_16x16x32_bf16(ah[i], bh[j], acc[i][j], 0, 0, 0);
                acc[i][j] = __builtin_amdgcn_mfma_f32_16x16x32_bf16(ah[i], bl[j], acc[i][j], 0, 0, 0);
                acc[i][j] = __builtin_amdgcn_mfma_f32_16x16x32_bf16(al[i], bh[j], acc[i][j], 0, 0, 0);
            }
    };

    constexpr int NT = K / 32;   // 24
    LOAD(0); STORE(0); __syncthreads();
    int buf = 0;
    for (int t = 0; t < NT; ++t) {
        if (t + 1 < NT) LOAD((t + 1) * 32);  // issue early: hides under MFMA
        COMPUTE(buf);
        if (t + 1 < NT) STORE(buf ^ 1);      // write late (other buffer, pre-barrier ok)
        __syncthreads();
        buf ^= 1;
    }

    // epilogue: D frag mapping col=lane&15, row=(lane>>4)*4+r  [m89-verified]
    const int erow = m0 + wr * 64 + ((lane >> 4) << 2);
    const int ecol = n0 + wc * 64 + (lane & 15);
    #pragma unroll
    for (int i = 0; i < 4; ++i)
        #pragma unroll
        for (int j = 0; j < 4; ++j)
            #pragma unroll
            for (int r = 0; r < 4; ++r) {
                float vv = acc[i][j][r];
                if (mode == 1) vv = 1.0f / (1.0f + __expf(-vv));
                out[(size_t)(erow + i * 16 + r) * N + (ecol + j * 16)] = vv;
            }
}

// ---------------------------------------------------------------------------
// WKV (unchanged math, verified in rounds 2-3)
// ---------------------------------------------------------------------------
#define WKV_STEP(a, bb, p, kt, vt, w)                \
    {                                                \
        const float pn = fmaxf((p) - (w), (kt));     \
        const float e1 = __expf((p) - (w) - pn);     \
        const float e2 = __expf((kt) - pn);          \
        (a)  = e1 * (a)  + e2 * (vt);                \
        (bb) = e1 * (bb) + e2;                       \
        (p)  = pn;                                   \
    }

__global__ __launch_bounds__(256) void wkv_phase1(
    const float* __restrict__ k, const float* __restrict__ v,
    const float* __restrict__ decay,
    float* __restrict__ Sfa, float* __restrict__ Sfb, float* __restrict__ Sfp,
    float* __restrict__ Sba, float* __restrict__ Sbb, float* __restrict__ Sbp) {
    const int c = blockIdx.x * 256 + threadIdx.x;
    const int j = blockIdx.y;
    const int b = blockIdx.z;
    const float w = decay[c] * (1.0f / (float)TLEN);

    const size_t base = ((size_t)b * TLEN + (size_t)j * LCH) * CDIM + c;
    float kt[LCH], vt[LCH];
    #pragma unroll
    for (int i = 0; i < LCH; ++i) {
        kt[i] = k[base + (size_t)i * CDIM];
        vt[i] = v[base + (size_t)i * CDIM];
    }

    const size_t idx = ((size_t)b * NCH + j) * CDIM + c;

    float a = 0.0f, bb = 0.0f, p = -1e38f;
    #pragma unroll
    for (int i = 0; i < LCH; ++i) WKV_STEP(a, bb, p, kt[i], vt[i], w);
    Sfa[idx] = a; Sfb[idx] = bb; Sfp[idx] = p;

    a = 0.0f; bb = 0.0f; p = -1e38f;
    #pragma unroll
    for (int i = LCH - 1; i >= 0; --i) WKV_STEP(a, bb, p, kt[i], vt[i], w);
    Sba[idx] = a; Sbb[idx] = bb; Sbp[idx] = p;
}

#define WKV_COMBINE(a, bb, p, as, bs, ps, wL)        \
    {                                                \
        const float pn = fmaxf((p) - (wL), (ps));    \
        const float e1 = __expf((p) - (wL) - pn);    \
        const float e2 = __expf((ps) - pn);          \
        (a)  = e1 * (a)  + e2 * (as);                \
        (bb) = e1 * (bb) + e2 * (bs);                \
        (p)  = pn;                                   \
    }

__global__ __launch_bounds__(64) void wkv_phase2(
    const float* __restrict__ Sfa, const float* __restrict__ Sfb, const float* __restrict__ Sfp,
    const float* __restrict__ Sba, const float* __restrict__ Sbb, const float* __restrict__ Sbp,
    const float* __restrict__ decay,
    float* __restrict__ Lina, float* __restrict__ Linb, float* __restrict__ Linp,
    float* __restrict__ Rina, float* __restrict__ Rinb, float* __restrict__ Rinp) {
    const int c = blockIdx.x * 64 + threadIdx.x;
    const int b = blockIdx.y;
    const float wL = decay[c] * ((float)LCH / (float)TLEN);

    {
        float a = 0.0f, bb = 0.0f, p = -1e38f;
        for (int j = 0; j < NCH; ++j) {
            const size_t idx = ((size_t)b * NCH + j) * CDIM + c;
            Lina[idx] = a; Linb[idx] = bb; Linp[idx] = p;
            WKV_COMBINE(a, bb, p, Sfa[idx], Sfb[idx], Sfp[idx], wL);
        }
    }
    {
        float a = 0.0f, bb = 0.0f, p = -1e38f;
        for (int j = NCH - 1; j >= 0; --j) {
            const size_t idx = ((size_t)b * NCH + j) * CDIM + c;
            Rina[idx] = a; Rinb[idx] = bb; Rinp[idx] = p;
            WKV_COMBINE(a, bb, p, Sba[idx], Sbb[idx], Sbp[idx], wL);
        }
    }
}

// phase3: combine + fuse z = sr*y, emitting z split to (zh, zl) bf16 for the
// final MFMA GEMM. zh/zl may alias xh/xl (dead after the 3 input GEMMs).
__global__ __launch_bounds__(256) void wkv_phase3(
    const float* __restrict__ k, const float* __restrict__ v,
    const float* __restrict__ sr,
    const float* __restrict__ Lina, const float* __restrict__ Linb, const float* __restrict__ Linp,
    const float* __restrict__ Rina, const float* __restrict__ Rinb, const float* __restrict__ Rinp,
    const float* __restrict__ decay, const float* __restrict__ first,
    unsigned short* __restrict__ zh, unsigned short* __restrict__ zl) {
    const int c = blockIdx.x * 256 + threadIdx.x;
    const int j = blockIdx.y;
    const int b = blockIdx.z;
    const float w = decay[c] * (1.0f / (float)TLEN);
    const float u = first[c] * (1.0f / (float)TLEN);

    const size_t base = ((size_t)b * TLEN + (size_t)j * LCH) * CDIM + c;
    float kt[LCH], vt[LCH];
    #pragma unroll
    for (int i = 0; i < LCH; ++i) {
        kt[i] = k[base + (size_t)i * CDIM];
        vt[i] = v[base + (size_t)i * CDIM];
    }

    const size_t idx = ((size_t)b * NCH + j) * CDIM + c;

    float ar[LCH], br[LCH], pr[LCH];
    {
        float a = Rina[idx], bb = Rinb[idx], p = Rinp[idx];
        #pragma unroll
        for (int i = LCH - 1; i >= 0; --i) {
            ar[i] = a; br[i] = bb; pr[i] = p;
            WKV_STEP(a, bb, p, kt[i], vt[i], w);
        }
    }
    {
        float a = Lina[idx], bb = Linb[idx], p = Linp[idx];
        #pragma unroll
        for (int i = 0; i < LCH; ++i) {
            const size_t off = base + (size_t)i * CDIM;
            const float srt = sr[off];
            const float ps = u + kt[i];
            const float q  = fmaxf(fmaxf(p, pr[i]), ps);
            const float eL = __expf(p - q);
            const float eR = __expf(pr[i] - q);
            const float eS = __expf(ps - q);
            const float num = eL * a  + eR * ar[i] + eS * vt[i];
            const float den = eL * bb + eR * br[i] + eS;
            const float zz = srt * (num / den);
            const unsigned short h = f2bf(zz);
            zh[off] = h;
            zl[off] = f2bf(zz - bf2f(h));
            WKV_STEP(a, bb, p, kt[i], vt[i], w);
        }
    }
}

// ---------------------------------------------------------------------------
// Driver. ws layout: [8 weight bf16 planes | per-chunk: k,v,sr f32; 12 state
// planes; xh,xl bf16 (aliased by zh,zl)]. Batch-chunked to fit ws_size.
// ---------------------------------------------------------------------------
extern "C" void kernel_launch(void* const* d_in, const int* in_sizes, int n_in,
                              void* d_out, int out_size, void* d_ws, size_t ws_size,
                              hipStream_t stream) {
    const float* x     = (const float*)d_in[0];
    const float* Wk    = (const float*)d_in[1];
    const float* Wv    = (const float*)d_in[2];
    const float* Wr    = (const float*)d_in[3];
    const float* Wo    = (const float*)d_in[4];
    const float* decay = (const float*)d_in[5];
    const float* first = (const float*)d_in[6];
    float* out = (float*)d_out;

    const size_t WN = (size_t)CDIM * CDIM;                    // 589824
    const size_t wbytes = 8 * WN * sizeof(unsigned short);    // 9.44 MB
    const size_t per_b  = (size_t)TLEN * CDIM * 16 + 12ull * NCH * CDIM * 4; // 29.9 MB
    if (ws_size < wbytes + per_b) return;
    int nb = (int)((ws_size - wbytes) / per_b);
    if (nb > BSZ) nb = BSZ;

    unsigned short* wsp = (unsigned short*)d_ws;
    unsigned short* Wkh = wsp + 0 * WN; unsigned short* Wkl = wsp + 1 * WN;
    unsigned short* Wvh = wsp + 2 * WN; unsigned short* Wvl = wsp + 3 * WN;
    unsigned short* Wrh = wsp + 4 * WN; unsigned short* Wrl = wsp + 5 * WN;
    unsigned short* Woh = wsp + 6 * WN; unsigned short* Wol = wsp + 7 * WN;

    const size_t NE = (size_t)nb * TLEN * CDIM;
    const size_t NP = (size_t)nb * NCH * CDIM;
    float* fbase = (float*)(wsp + 8 * WN);
    float* kk  = fbase;
    float* vv  = kk + NE;
    float* sr  = vv + NE;
    float* Sfa = sr + NE;               float* Sfb = Sfa + NP;  float* Sfp = Sfb + NP;
    float* Sba = Sfp + NP;              float* Sbb = Sba + NP;  float* Sbp = Sbb + NP;
    float* Lina = Sbp + NP;             float* Linb = Lina + NP; float* Linp = Linb + NP;
    float* Rina = Linp + NP;            float* Rinb = Rina + NP; float* Rinp = Rinb + NP;
    unsigned short* xh = (unsigned short*)(Rinp + NP);
    unsigned short* xl = xh + NE;
    unsigned short* zh = xh;  // alias: phase3 runs after the 3 input GEMMs
    unsigned short* zl = xl;

    // weight splits (once)
    split_f32<<<dim3((int)(WN / 1024)), dim3(256), 0, stream>>>(Wk, Wkh, Wkl, (int)(WN / 4));
    split_f32<<<dim3((int)(WN / 1024)), dim3(256), 0, stream>>>(Wv, Wvh, Wvl, (int)(WN / 4));
    split_f32<<<dim3((int)(WN / 1024)), dim3(256), 0, stream>>>(Wr, Wrh, Wrl, (int)(WN / 4));
    split_f32<<<dim3((int)(WN / 1024)), dim3(256), 0, stream>>>(Wo, Woh, Wol, (int)(WN / 4));

    for (int b0 = 0; b0 < BSZ; b0 += nb) {
        const int curb = (BSZ - b0 < nb) ? (BSZ - b0) : nb;
        const int rows = curb * TLEN;
        const float* xc = x   + (size_t)b0 * TLEN * CDIM;
        float*       oc = out + (size_t)b0 * TLEN * CDIM;

        const int n4 = rows * CDIM / 4;
        split_f32<<<dim3(n4 / 256), dim3(256), 0, stream>>>(xc, xh, xl, n4);

        dim3 ggrid(CDIM / 128, rows / 128);
        gemm_mfma_split<<<ggrid, dim3(256), 0, stream>>>(xh, xl, Wkh, Wkl, kk, 0);
        gemm_mfma_split<<<ggrid, dim3(256), 0, stream>>>(xh, xl, Wvh, Wvl, vv, 0);
        gemm_mfma_split<<<ggrid, dim3(256), 0, stream>>>(xh, xl, Wrh, Wrl, sr, 1);

        wkv_phase1<<<dim3(CDIM / 256, NCH, curb), dim3(256), 0, stream>>>(
            kk, vv, decay, Sfa, Sfb, Sfp, Sba, Sbb, Sbp);
        wkv_phase2<<<dim3(CDIM / 64, curb), dim3(64), 0, stream>>>(
            Sfa, Sfb, Sfp, Sba, Sbb, Sbp, decay,
            Lina, Linb, Linp, Rina, Rinb, Rinp);
        wkv_phase3<<<dim3(CDIM / 256, NCH, curb), dim3(256), 0, stream>>>(
            kk, vv, sr, Lina, Linb, Linp, Rina, Rinb, Rinp, decay, first, zh, zl);

        gemm_mfma_split<<<ggrid, dim3(256), 0, stream>>>(zh, zl, Woh, Wol, oc, 0);
    }
}

// Round 5
// 372.505 us; speedup vs baseline: 10.0487x; 1.2624x over previous
//
#include <hip/hip_runtime.h>

#define BSZ 8
#define TLEN 2048
#define CDIM 768
#define LCH 16
#define NCH (TLEN / LCH)

typedef __attribute__((ext_vector_type(4))) float f32x4;
typedef __attribute__((ext_vector_type(8))) short bf16x8;   // 8 bf16 = 4 VGPRs (MFMA operand)
typedef __attribute__((ext_vector_type(4))) unsigned short us4;
typedef __attribute__((ext_vector_type(4))) float float4v;

__device__ __forceinline__ unsigned short f2bf(float f) {
    unsigned int u = __float_as_uint(f);
    u += 0x7fffu + ((u >> 16) & 1u);   // RNE
    return (unsigned short)(u >> 16);
}
__device__ __forceinline__ float bf2f(unsigned short h) {
    return __uint_as_float(((unsigned int)h) << 16);
}

// async global->LDS, 16B per lane; LDS dest = base + lane*16 (wave-linear)
#define GLD16(g, l)                                                          \
    __builtin_amdgcn_global_load_lds(                                        \
        (const __attribute__((address_space(1))) unsigned int*)(g),          \
        (__attribute__((address_space(3))) unsigned int*)(l), 16, 0, 0)

// ---------------------------------------------------------------------------
// split f32 -> (hi, lo) bf16, 4 elements/thread. n4 = n/4.
// ---------------------------------------------------------------------------
__global__ __launch_bounds__(256) void split_f32(const float* __restrict__ src,
                                                 unsigned short* __restrict__ hi,
                                                 unsigned short* __restrict__ lo,
                                                 int n4) {
    int i = blockIdx.x * 256 + threadIdx.x;
    if (i >= n4) return;
    float4v f = ((const float4v*)src)[i];
    us4 h, l;
    #pragma unroll
    for (int j = 0; j < 4; ++j) {
        unsigned short hh = f2bf(f[j]);
        h[j] = hh;
        l[j] = f2bf(f[j] - bf2f(hh));
    }
    ((us4*)hi)[i] = h;
    ((us4*)lo)[i] = l;
}

// ---------------------------------------------------------------------------
// Split-precision MFMA GEMM (NT): out[m,n] = sum_k A[m,k]*W[n,k], A=Ah+Al,
// W=Wh+Wl (bf16), fp32 accum via 3 MFMAs (hh, hl, lh). N=K=CDIM.
// 128x128 tile, BK=32, 4 waves. Staging via global_load_lds dwordx4 with
// pre-swizzled global source (linear LDS dest); ds_read uses the same
// involution kq ^= (row>>2)&3 -> conflict-floor b128 reads.
// XCD-bijective block remap: bid=(xcd,lj); mtile = xcd*mpx + lj/6, ntile=lj%6.
// mode 1: sigmoid epilogue.
// ---------------------------------------------------------------------------
__global__ __launch_bounds__(256) void gemm_mfma_split(
    const unsigned short* __restrict__ Ah, const unsigned short* __restrict__ Al,
    const unsigned short* __restrict__ Wh, const unsigned short* __restrict__ Wl,
    float* __restrict__ out, int mpx, int mode) {
    constexpr int K = CDIM, N = CDIM;
    __shared__ __align__(16) char smem[2][4][8192];  // [buf][Ah,Al,Wh,Wl][128*32*2B]

    const int tid  = threadIdx.x;
    const int lane = tid & 63;
    const int wid  = tid >> 6;

    const int bid = blockIdx.x;
    const int xcd = bid & 7;
    const int lj  = bid >> 3;
    const int m0 = (xcd * mpx + lj / 6) * 128;
    const int n0 = (lj % 6) * 128;

    // staging: wave `wid` owns plane `wid` (0=Ah,1=Al,2=Wh,3=Wl)
    const unsigned short* gsrc = (wid == 0) ? Ah : (wid == 1) ? Al : (wid == 2) ? Wh : Wl;
    const int rbase = (wid < 2) ? m0 : n0;

    // per-lane pre-swizzled source byte offset (row = q*16 + lane>>2, so the
    // swizzle selector (row>>2)&3 == (lane>>4)&3, independent of q):
    const int gq = (lane & 3) ^ ((lane >> 4) & 3);
    const unsigned int goff0 =
        (unsigned int)(((rbase + (lane >> 2)) * K + gq * 8) * 2);
    const char* gbase = (const char*)gsrc;

    auto STAGE = [&](int buf, unsigned int off) {
        char* lb = &smem[buf][wid][0];
        #pragma unroll
        for (int q = 0; q < 8; ++q)                 // q: 16-row stripes (+24576 B)
            GLD16(gbase + off + q * 24576, lb + q * 1024);
    };

    const int wr = wid >> 1, wc = wid & 1;
    f32x4 acc[4][4];
    #pragma unroll
    for (int i = 0; i < 4; ++i)
        #pragma unroll
        for (int j = 0; j < 4; ++j)
            acc[i][j] = (f32x4){0.f, 0.f, 0.f, 0.f};

    // fragment read: row = wbase + i*16 + (lane&15); kq = (lane>>4) ^ ((row>>2)&3)
    const int rl   = lane & 15;
    const int kofs = (((lane >> 4) ^ ((rl >> 2) & 3)) << 4);
    const int ra   = (wr * 64 + rl) * 64;           // byte base, A row
    const int rb   = (wc * 64 + rl) * 64;           // byte base, W row

    auto COMPUTE = [&](int buf) {
        const char* sAh = &smem[buf][0][0];
        const char* sAl = &smem[buf][1][0];
        const char* sWh = &smem[buf][2][0];
        const char* sWl = &smem[buf][3][0];
        bf16x8 ah[4], al[4], bh[4], bl[4];
        #pragma unroll
        for (int i = 0; i < 4; ++i) {
            ah[i] = *(const bf16x8*)(sAh + ra + i * 1024 + kofs);
            al[i] = *(const bf16x8*)(sAl + ra + i * 1024 + kofs);
            bh[i] = *(const bf16x8*)(sWh + rb + i * 1024 + kofs);
            bl[i] = *(const bf16x8*)(sWl + rb + i * 1024 + kofs);
        }
        #pragma unroll
        for (int i = 0; i < 4; ++i)
            #pragma unroll
            for (int j = 0; j < 4; ++j) {
                acc[i][j] = __builtin_amdgcn_mfma_f32_16x16x32_bf16(ah[i], bh[j], acc[i][j], 0, 0, 0);
                acc[i][j] = __builtin_amdgcn_mfma_f32_16x16x32_bf16(ah[i], bl[j], acc[i][j], 0, 0, 0);
                acc[i][j] = __builtin_amdgcn_mfma_f32_16x16x32_bf16(al[i], bh[j], acc[i][j], 0, 0, 0);
            }
    };

    constexpr int NT = K / 32;   // 24
    STAGE(0, goff0);
    __syncthreads();             // drains vmcnt (compiler-inserted)
    int buf = 0;
    for (int t = 0; t < NT; ++t) {
        if (t + 1 < NT) STAGE(buf ^ 1, goff0 + (unsigned int)(t + 1) * 64);
        COMPUTE(buf);            // ds_read+MFMA hides the in-flight DMA
        __syncthreads();         // vmcnt(0)+lgkmcnt(0)+barrier: next buf ready
        buf ^= 1;
    }

    // epilogue: D frag mapping col=lane&15, row=(lane>>4)*4+r
    const int erow = m0 + wr * 64 + ((lane >> 4) << 2);
    const int ecol = n0 + wc * 64 + (lane & 15);
    #pragma unroll
    for (int i = 0; i < 4; ++i)
        #pragma unroll
        for (int j = 0; j < 4; ++j)
            #pragma unroll
            for (int r = 0; r < 4; ++r) {
                float vv = acc[i][j][r];
                if (mode == 1) vv = 1.0f / (1.0f + __expf(-vv));
                out[(size_t)(erow + i * 16 + r) * N + (ecol + j * 16)] = vv;
            }
}

// ---------------------------------------------------------------------------
// WKV (math verified rounds 2-4)
// ---------------------------------------------------------------------------
#define WKV_STEP(a, bb, p, kt, vt, w)                \
    {                                                \
        const float pn = fmaxf((p) - (w), (kt));     \
        const float e1 = __expf((p) - (w) - pn);     \
        const float e2 = __expf((kt) - pn);          \
        (a)  = e1 * (a)  + e2 * (vt);                \
        (bb) = e1 * (bb) + e2;                       \
        (p)  = pn;                                   \
    }

__global__ __launch_bounds__(256) void wkv_phase1(
    const float* __restrict__ k, const float* __restrict__ v,
    const float* __restrict__ decay,
    float* __restrict__ Sfa, float* __restrict__ Sfb, float* __restrict__ Sfp,
    float* __restrict__ Sba, float* __restrict__ Sbb, float* __restrict__ Sbp) {
    const int c = blockIdx.x * 256 + threadIdx.x;
    const int j = blockIdx.y;
    const int b = blockIdx.z;
    const float w = decay[c] * (1.0f / (float)TLEN);

    const size_t base = ((size_t)b * TLEN + (size_t)j * LCH) * CDIM + c;
    float kt[LCH], vt[LCH];
    #pragma unroll
    for (int i = 0; i < LCH; ++i) {
        kt[i] = k[base + (size_t)i * CDIM];
        vt[i] = v[base + (size_t)i * CDIM];
    }

    const size_t idx = ((size_t)b * NCH + j) * CDIM + c;

    float a = 0.0f, bb = 0.0f, p = -1e38f;
    #pragma unroll
    for (int i = 0; i < LCH; ++i) WKV_STEP(a, bb, p, kt[i], vt[i], w);
    Sfa[idx] = a; Sfb[idx] = bb; Sfp[idx] = p;

    a = 0.0f; bb = 0.0f; p = -1e38f;
    #pragma unroll
    for (int i = LCH - 1; i >= 0; --i) WKV_STEP(a, bb, p, kt[i], vt[i], w);
    Sba[idx] = a; Sbb[idx] = bb; Sbp[idx] = p;
}

#define WKV_COMBINE(a, bb, p, as, bs, ps, wL)        \
    {                                                \
        const float pn = fmaxf((p) - (wL), (ps));    \
        const float e1 = __expf((p) - (wL) - pn);    \
        const float e2 = __expf((ps) - pn);          \
        (a)  = e1 * (a)  + e2 * (as);                \
        (bb) = e1 * (bb) + e2 * (bs);                \
        (p)  = pn;                                   \
    }

// blockIdx.z selects direction (0=forward, 1=backward): halves serial latency
__global__ __launch_bounds__(64) void wkv_phase2(
    const float* __restrict__ Sfa, const float* __restrict__ Sfb, const float* __restrict__ Sfp,
    const float* __restrict__ Sba, const float* __restrict__ Sbb, const float* __restrict__ Sbp,
    const float* __restrict__ decay,
    float* __restrict__ Lina, float* __restrict__ Linb, float* __restrict__ Linp,
    float* __restrict__ Rina, float* __restrict__ Rinb, float* __restrict__ Rinp) {
    const int c = blockIdx.x * 64 + threadIdx.x;
    const int b = blockIdx.y;
    const float wL = decay[c] * ((float)LCH / (float)TLEN);

    if (blockIdx.z == 0) {
        float a = 0.0f, bb = 0.0f, p = -1e38f;
        for (int j = 0; j < NCH; ++j) {
            const size_t idx = ((size_t)b * NCH + j) * CDIM + c;
            Lina[idx] = a; Linb[idx] = bb; Linp[idx] = p;
            WKV_COMBINE(a, bb, p, Sfa[idx], Sfb[idx], Sfp[idx], wL);
        }
    } else {
        float a = 0.0f, bb = 0.0f, p = -1e38f;
        for (int j = NCH - 1; j >= 0; --j) {
            const size_t idx = ((size_t)b * NCH + j) * CDIM + c;
            Rina[idx] = a; Rinb[idx] = bb; Rinp[idx] = p;
            WKV_COMBINE(a, bb, p, Sba[idx], Sbb[idx], Sbp[idx], wL);
        }
    }
}

// phase3: combine + fuse z = sr*y, emitting z split to (zh, zl) bf16 for the
// final MFMA GEMM. zh/zl alias xh/xl (dead after the 3 input GEMMs).
__global__ __launch_bounds__(256) void wkv_phase3(
    const float* __restrict__ k, const float* __restrict__ v,
    const float* __restrict__ sr,
    const float* __restrict__ Lina, const float* __restrict__ Linb, const float* __restrict__ Linp,
    const float* __restrict__ Rina, const float* __restrict__ Rinb, const float* __restrict__ Rinp,
    const float* __restrict__ decay, const float* __restrict__ first,
    unsigned short* __restrict__ zh, unsigned short* __restrict__ zl) {
    const int c = blockIdx.x * 256 + threadIdx.x;
    const int j = blockIdx.y;
    const int b = blockIdx.z;
    const float w = decay[c] * (1.0f / (float)TLEN);
    const float u = first[c] * (1.0f / (float)TLEN);

    const size_t base = ((size_t)b * TLEN + (size_t)j * LCH) * CDIM + c;
    float kt[LCH], vt[LCH];
    #pragma unroll
    for (int i = 0; i < LCH; ++i) {
        kt[i] = k[base + (size_t)i * CDIM];
        vt[i] = v[base + (size_t)i * CDIM];
    }

    const size_t idx = ((size_t)b * NCH + j) * CDIM + c;

    float ar[LCH], br[LCH], pr[LCH];
    {
        float a = Rina[idx], bb = Rinb[idx], p = Rinp[idx];
        #pragma unroll
        for (int i = LCH - 1; i >= 0; --i) {
            ar[i] = a; br[i] = bb; pr[i] = p;
            WKV_STEP(a, bb, p, kt[i], vt[i], w);
        }
    }
    {
        float a = Lina[idx], bb = Linb[idx], p = Linp[idx];
        #pragma unroll
        for (int i = 0; i < LCH; ++i) {
            const size_t off = base + (size_t)i * CDIM;
            const float srt = sr[off];
            const float ps = u + kt[i];
            const float q  = fmaxf(fmaxf(p, pr[i]), ps);
            const float eL = __expf(p - q);
            const float eR = __expf(pr[i] - q);
            const float eS = __expf(ps - q);
            const float num = eL * a  + eR * ar[i] + eS * vt[i];
            const float den = eL * bb + eR * br[i] + eS;
            const float zz = srt * (num / den);
            const unsigned short h = f2bf(zz);
            zh[off] = h;
            zl[off] = f2bf(zz - bf2f(h));
            WKV_STEP(a, bb, p, kt[i], vt[i], w);
        }
    }
}

// ---------------------------------------------------------------------------
// Driver. ws layout: [8 weight bf16 planes | per-chunk: k,v,sr f32; 12 state
// planes; xh,xl bf16 (aliased by zh,zl)]. Batch-chunked to fit ws_size.
// ---------------------------------------------------------------------------
extern "C" void kernel_launch(void* const* d_in, const int* in_sizes, int n_in,
                              void* d_out, int out_size, void* d_ws, size_t ws_size,
                              hipStream_t stream) {
    const float* x     = (const float*)d_in[0];
    const float* Wk    = (const float*)d_in[1];
    const float* Wv    = (const float*)d_in[2];
    const float* Wr    = (const float*)d_in[3];
    const float* Wo    = (const float*)d_in[4];
    const float* decay = (const float*)d_in[5];
    const float* first = (const float*)d_in[6];
    float* out = (float*)d_out;

    const size_t WN = (size_t)CDIM * CDIM;
    const size_t wbytes = 8 * WN * sizeof(unsigned short);
    const size_t per_b  = (size_t)TLEN * CDIM * 16 + 12ull * NCH * CDIM * 4;
    if (ws_size < wbytes + per_b) return;
    int nb = (int)((ws_size - wbytes) / per_b);
    if (nb > BSZ) nb = BSZ;

    unsigned short* wsp = (unsigned short*)d_ws;
    unsigned short* Wkh = wsp + 0 * WN; unsigned short* Wkl = wsp + 1 * WN;
    unsigned short* Wvh = wsp + 2 * WN; unsigned short* Wvl = wsp + 3 * WN;
    unsigned short* Wrh = wsp + 4 * WN; unsigned short* Wrl = wsp + 5 * WN;
    unsigned short* Woh = wsp + 6 * WN; unsigned short* Wol = wsp + 7 * WN;

    const size_t NE = (size_t)nb * TLEN * CDIM;
    const size_t NP = (size_t)nb * NCH * CDIM;
    float* fbase = (float*)(wsp + 8 * WN);
    float* kk  = fbase;
    float* vv  = kk + NE;
    float* sr  = vv + NE;
    float* Sfa = sr + NE;               float* Sfb = Sfa + NP;  float* Sfp = Sfb + NP;
    float* Sba = Sfp + NP;              float* Sbb = Sba + NP;  float* Sbp = Sbb + NP;
    float* Lina = Sbp + NP;             float* Linb = Lina + NP; float* Linp = Linb + NP;
    float* Rina = Linp + NP;            float* Rinb = Rina + NP; float* Rinp = Rinb + NP;
    unsigned short* xh = (unsigned short*)(Rinp + NP);
    unsigned short* xl = xh + NE;
    unsigned short* zh = xh;  // alias: phase3 runs after the 3 input GEMMs
    unsigned short* zl = xl;

    split_f32<<<dim3((int)(WN / 1024)), dim3(256), 0, stream>>>(Wk, Wkh, Wkl, (int)(WN / 4));
    split_f32<<<dim3((int)(WN / 1024)), dim3(256), 0, stream>>>(Wv, Wvh, Wvl, (int)(WN / 4));
    split_f32<<<dim3((int)(WN / 1024)), dim3(256), 0, stream>>>(Wr, Wrh, Wrl, (int)(WN / 4));
    split_f32<<<dim3((int)(WN / 1024)), dim3(256), 0, stream>>>(Wo, Woh, Wol, (int)(WN / 4));

    for (int b0 = 0; b0 < BSZ; b0 += nb) {
        const int curb = (BSZ - b0 < nb) ? (BSZ - b0) : nb;
        const int rows = curb * TLEN;
        const float* xc = x   + (size_t)b0 * TLEN * CDIM;
        float*       oc = out + (size_t)b0 * TLEN * CDIM;

        const int n4 = rows * CDIM / 4;
        split_f32<<<dim3(n4 / 256), dim3(256), 0, stream>>>(xc, xh, xl, n4);

        const int nblk = (rows / 128) * 6;     // divisible by 8 for any curb
        const int mpx  = (rows / 128) / 8;     // mtiles per XCD
        gemm_mfma_split<<<dim3(nblk), dim3(256), 0, stream>>>(xh, xl, Wkh, Wkl, kk, mpx, 0);
        gemm_mfma_split<<<dim3(nblk), dim3(256), 0, stream>>>(xh, xl, Wvh, Wvl, vv, mpx, 0);
        gemm_mfma_split<<<dim3(nblk), dim3(256), 0, stream>>>(xh, xl, Wrh, Wrl, sr, mpx, 1);

        wkv_phase1<<<dim3(CDIM / 256, NCH, curb), dim3(256), 0, stream>>>(
            kk, vv, decay, Sfa, Sfb, Sfp, Sba, Sbb, Sbp);
        wkv_phase2<<<dim3(CDIM / 64, curb, 2), dim3(64), 0, stream>>>(
            Sfa, Sfb, Sfp, Sba, Sbb, Sbp, decay,
            Lina, Linb, Linp, Rina, Rinb, Rinp);
        wkv_phase3<<<dim3(CDIM / 256, NCH, curb), dim3(256), 0, stream>>>(
            kk, vv, sr, Lina, Linb, Linp, Rina, Rinb, Rinp, decay, first, zh, zl);

        gemm_mfma_split<<<dim3(nblk), dim3(256), 0, stream>>>(zh, zl, Woh, Wol, oc, mpx, 0);
    }
}

// Round 6
// 326.483 us; speedup vs baseline: 11.4652x; 1.1410x over previous
//
#include <hip/hip_runtime.h>

#define BSZ 8
#define TLEN 2048
#define CDIM 768
#define LCH 16
#define NCH (TLEN / LCH)

typedef __attribute__((ext_vector_type(4))) float f32x4;
typedef __attribute__((ext_vector_type(8))) short bf16x8;   // 8 bf16 = 4 VGPRs (MFMA operand)
typedef __attribute__((ext_vector_type(4))) unsigned short us4;
typedef __attribute__((ext_vector_type(4))) float float4v;

__device__ __forceinline__ unsigned short f2bf(float f) {
    unsigned int u = __float_as_uint(f);
    u += 0x7fffu + ((u >> 16) & 1u);   // RNE
    return (unsigned short)(u >> 16);
}
__device__ __forceinline__ float bf2f(unsigned short h) {
    return __uint_as_float(((unsigned int)h) << 16);
}

// async global->LDS, 16B per lane; LDS dest = base + lane*16 (wave-linear)
#define GLD16(g, l)                                                          \
    __builtin_amdgcn_global_load_lds(                                        \
        (const __attribute__((address_space(1))) unsigned int*)(g),          \
        (__attribute__((address_space(3))) unsigned int*)(l), 16, 0, 0)

// ---------------------------------------------------------------------------
// split f32 -> (hi, lo) bf16, 4 elements/thread. n4 = n/4.
// ---------------------------------------------------------------------------
__global__ __launch_bounds__(256) void split_f32(const float* __restrict__ src,
                                                 unsigned short* __restrict__ hi,
                                                 unsigned short* __restrict__ lo,
                                                 int n4) {
    int i = blockIdx.x * 256 + threadIdx.x;
    if (i >= n4) return;
    float4v f = ((const float4v*)src)[i];
    us4 h, l;
    #pragma unroll
    for (int j = 0; j < 4; ++j) {
        unsigned short hh = f2bf(f[j]);
        h[j] = hh;
        l[j] = f2bf(f[j] - bf2f(hh));
    }
    ((us4*)hi)[i] = h;
    ((us4*)lo)[i] = l;
}

// ---------------------------------------------------------------------------
// Split-precision MFMA GEMM (NT): out[m,n] = sum_k A[m,k]*W[n,k], A=Ah+Al,
// W=Wh+Wl (bf16), fp32 accum via 3 MFMAs (hh, hl, lh). N=K=CDIM.
// 256x192 tile, BK=32, 8 waves (512 thr), wave tile 64x96 (4x6 frags).
// Staging: global_load_lds dwordx4, linear LDS dest, inverse-swizzled global
// source; ds_read applies the same involution kq ^= (rl>>2)&3.
// LDS: 2 bufs x 56KB = 112KB -> 1 block/CU, 2 waves/SIMD.
// Grid: (rows/256)*4 blocks == 1 block/CU at rows=16384.
// mode 1: sigmoid epilogue.
// ---------------------------------------------------------------------------
__global__ __launch_bounds__(512, 2) void gemm_mfma_split(
    const unsigned short* __restrict__ Ah, const unsigned short* __restrict__ Al,
    const unsigned short* __restrict__ Wh, const unsigned short* __restrict__ Wl,
    float* __restrict__ out, int mpx, int mode) {
    constexpr int K = CDIM, N = CDIM;
    // buffer layout (bytes): Ah[256][64] @0, Al @16384, Bh[192][64] @32768, Bl @45056
    __shared__ __align__(16) char smem[2][57344];

    const int tid  = threadIdx.x;
    const int lane = tid & 63;
    const int wid  = tid >> 6;

    const int bid = blockIdx.x;
    const int xcd = bid & 7;
    const int lj  = bid >> 3;
    const int m0 = (xcd * mpx + (lj >> 2)) * 256;
    const int n0 = (lj & 3) * 192;

    // ---- staging role: plane pl = wid>>1 (0=Ah,1=Al,2=Bh,3=Bl), half = wid&1
    const int pl   = wid >> 1;
    const int half = wid & 1;
    const unsigned short* gsrc = (pl == 0) ? Ah : (pl == 1) ? Al : (pl == 2) ? Wh : Wl;
    const int row0   = ((pl < 2) ? m0 : n0) + half * ((pl < 2) ? 128 : 96);
    const int plbase = ((pl == 0) ? 0 : (pl == 1) ? 16384 : (pl == 2) ? 32768 : 45056)
                     + half * ((pl < 2) ? 8192 : 6144);

    // per-lane pre-swizzled global byte offset; selector (row>>2)&3 == (lane>>4)&3
    const int gq = (lane & 3) ^ ((lane >> 4) & 3);
    const char* gb = (const char*)gsrc
                   + (size_t)(row0 + (lane >> 2)) * (K * 2) + gq * 16;

    auto STAGE = [&](int buf, int k0) {
        char* lb = &smem[buf][plbase];
        const char* g = gb + k0 * 2;
        if (pl < 2) {
            #pragma unroll
            for (int q = 0; q < 8; ++q)              // 16-row stripes
                GLD16(g + q * 24576, lb + q * 1024);
        } else {
            #pragma unroll
            for (int q = 0; q < 6; ++q)
                GLD16(g + q * 24576, lb + q * 1024);
        }
    };

    // ---- compute role: wr = wid>>1 (0..3, 64-row group), wc = wid&1 (96-col group)
    const int wr = wid >> 1, wc = wid & 1;
    const int rl   = lane & 15;
    const int kofs = (((lane >> 4) ^ ((rl >> 2) & 3)) << 4);

    f32x4 acc[4][6];
    #pragma unroll
    for (int i = 0; i < 4; ++i)
        #pragma unroll
        for (int j = 0; j < 6; ++j)
            acc[i][j] = (f32x4){0.f, 0.f, 0.f, 0.f};

    auto COMPUTE = [&](int buf) {
        const char* sb = &smem[buf][0];
        bf16x8 a_h[4], a_l[4], b_h[6], b_l[6];
        #pragma unroll
        for (int fi = 0; fi < 4; ++fi) {
            const int off = (wr * 64 + fi * 16 + rl) * 64 + kofs;
            a_h[fi] = *(const bf16x8*)(sb + off);
            a_l[fi] = *(const bf16x8*)(sb + 16384 + off);
        }
        #pragma unroll
        for (int fj = 0; fj < 6; ++fj) {
            const int off = (wc * 96 + fj * 16 + rl) * 64 + kofs;
            b_h[fj] = *(const bf16x8*)(sb + 32768 + off);
            b_l[fj] = *(const bf16x8*)(sb + 45056 + off);
        }
        __builtin_amdgcn_s_setprio(1);
        #pragma unroll
        for (int fi = 0; fi < 4; ++fi)
            #pragma unroll
            for (int fj = 0; fj < 6; ++fj)
                acc[fi][fj] = __builtin_amdgcn_mfma_f32_16x16x32_bf16(a_h[fi], b_h[fj], acc[fi][fj], 0, 0, 0);
        #pragma unroll
        for (int fi = 0; fi < 4; ++fi)
            #pragma unroll
            for (int fj = 0; fj < 6; ++fj)
                acc[fi][fj] = __builtin_amdgcn_mfma_f32_16x16x32_bf16(a_h[fi], b_l[fj], acc[fi][fj], 0, 0, 0);
        #pragma unroll
        for (int fi = 0; fi < 4; ++fi)
            #pragma unroll
            for (int fj = 0; fj < 6; ++fj)
                acc[fi][fj] = __builtin_amdgcn_mfma_f32_16x16x32_bf16(a_l[fi], b_h[fj], acc[fi][fj], 0, 0, 0);
        __builtin_amdgcn_s_setprio(0);
    };

    constexpr int NT = K / 32;   // 24
    STAGE(0, 0);
    __syncthreads();
    int buf = 0;
    for (int t = 0; t < NT; ++t) {
        if (t + 1 < NT) STAGE(buf ^ 1, (t + 1) * 32);
        COMPUTE(buf);
        __syncthreads();
        buf ^= 1;
    }

    // epilogue: D frag mapping col=lane&15, row=(lane>>4)*4+r
    const int erow = m0 + wr * 64 + ((lane >> 4) << 2);
    const int ecol = n0 + wc * 96 + rl;
    #pragma unroll
    for (int fi = 0; fi < 4; ++fi)
        #pragma unroll
        for (int fj = 0; fj < 6; ++fj)
            #pragma unroll
            for (int r = 0; r < 4; ++r) {
                float vv = acc[fi][fj][r];
                if (mode == 1) vv = 1.0f / (1.0f + __expf(-vv));
                out[(size_t)(erow + fi * 16 + r) * N + (ecol + fj * 16)] = vv;
            }
}

// ---------------------------------------------------------------------------
// WKV (math verified rounds 2-5)
// ---------------------------------------------------------------------------
#define WKV_STEP(a, bb, p, kt, vt, w)                \
    {                                                \
        const float pn = fmaxf((p) - (w), (kt));     \
        const float e1 = __expf((p) - (w) - pn);     \
        const float e2 = __expf((kt) - pn);          \
        (a)  = e1 * (a)  + e2 * (vt);                \
        (bb) = e1 * (bb) + e2;                       \
        (p)  = pn;                                   \
    }

__global__ __launch_bounds__(256) void wkv_phase1(
    const float* __restrict__ k, const float* __restrict__ v,
    const float* __restrict__ decay,
    float* __restrict__ Sfa, float* __restrict__ Sfb, float* __restrict__ Sfp,
    float* __restrict__ Sba, float* __restrict__ Sbb, float* __restrict__ Sbp) {
    const int c = blockIdx.x * 256 + threadIdx.x;
    const int j = blockIdx.y;
    const int b = blockIdx.z;
    const float w = decay[c] * (1.0f / (float)TLEN);

    const size_t base = ((size_t)b * TLEN + (size_t)j * LCH) * CDIM + c;
    float kt[LCH], vt[LCH];
    #pragma unroll
    for (int i = 0; i < LCH; ++i) {
        kt[i] = k[base + (size_t)i * CDIM];
        vt[i] = v[base + (size_t)i * CDIM];
    }

    const size_t idx = ((size_t)b * NCH + j) * CDIM + c;

    float a = 0.0f, bb = 0.0f, p = -1e38f;
    #pragma unroll
    for (int i = 0; i < LCH; ++i) WKV_STEP(a, bb, p, kt[i], vt[i], w);
    Sfa[idx] = a; Sfb[idx] = bb; Sfp[idx] = p;

    a = 0.0f; bb = 0.0f; p = -1e38f;
    #pragma unroll
    for (int i = LCH - 1; i >= 0; --i) WKV_STEP(a, bb, p, kt[i], vt[i], w);
    Sba[idx] = a; Sbb[idx] = bb; Sbp[idx] = p;
}

#define WKV_COMBINE(a, bb, p, as, bs, ps, wL)        \
    {                                                \
        const float pn = fmaxf((p) - (wL), (ps));    \
        const float e1 = __expf((p) - (wL) - pn);    \
        const float e2 = __expf((ps) - pn);          \
        (a)  = e1 * (a)  + e2 * (as);                \
        (bb) = e1 * (bb) + e2 * (bs);                \
        (p)  = pn;                                   \
    }

// blockIdx.z selects direction (0=forward, 1=backward)
__global__ __launch_bounds__(64) void wkv_phase2(
    const float* __restrict__ Sfa, const float* __restrict__ Sfb, const float* __restrict__ Sfp,
    const float* __restrict__ Sba, const float* __restrict__ Sbb, const float* __restrict__ Sbp,
    const float* __restrict__ decay,
    float* __restrict__ Lina, float* __restrict__ Linb, float* __restrict__ Linp,
    float* __restrict__ Rina, float* __restrict__ Rinb, float* __restrict__ Rinp) {
    const int c = blockIdx.x * 64 + threadIdx.x;
    const int b = blockIdx.y;
    const float wL = decay[c] * ((float)LCH / (float)TLEN);

    if (blockIdx.z == 0) {
        float a = 0.0f, bb = 0.0f, p = -1e38f;
        for (int j = 0; j < NCH; ++j) {
            const size_t idx = ((size_t)b * NCH + j) * CDIM + c;
            Lina[idx] = a; Linb[idx] = bb; Linp[idx] = p;
            WKV_COMBINE(a, bb, p, Sfa[idx], Sfb[idx], Sfp[idx], wL);
        }
    } else {
        float a = 0.0f, bb = 0.0f, p = -1e38f;
        for (int j = NCH - 1; j >= 0; --j) {
            const size_t idx = ((size_t)b * NCH + j) * CDIM + c;
            Rina[idx] = a; Rinb[idx] = bb; Rinp[idx] = p;
            WKV_COMBINE(a, bb, p, Sba[idx], Sbb[idx], Sbp[idx], wL);
        }
    }
}

// phase3: combine + fuse z = sr*y, emitting z split to (zh, zl) bf16 for the
// final MFMA GEMM. zh/zl alias xh/xl (dead after the 3 input GEMMs).
__global__ __launch_bounds__(256) void wkv_phase3(
    const float* __restrict__ k, const float* __restrict__ v,
    const float* __restrict__ sr,
    const float* __restrict__ Lina, const float* __restrict__ Linb, const float* __restrict__ Linp,
    const float* __restrict__ Rina, const float* __restrict__ Rinb, const float* __restrict__ Rinp,
    const float* __restrict__ decay, const float* __restrict__ first,
    unsigned short* __restrict__ zh, unsigned short* __restrict__ zl) {
    const int c = blockIdx.x * 256 + threadIdx.x;
    const int j = blockIdx.y;
    const int b = blockIdx.z;
    const float w = decay[c] * (1.0f / (float)TLEN);
    const float u = first[c] * (1.0f / (float)TLEN);

    const size_t base = ((size_t)b * TLEN + (size_t)j * LCH) * CDIM + c;
    float kt[LCH], vt[LCH];
    #pragma unroll
    for (int i = 0; i < LCH; ++i) {
        kt[i] = k[base + (size_t)i * CDIM];
        vt[i] = v[base + (size_t)i * CDIM];
    }

    const size_t idx = ((size_t)b * NCH + j) * CDIM + c;

    float ar[LCH], br[LCH], pr[LCH];
    {
        float a = Rina[idx], bb = Rinb[idx], p = Rinp[idx];
        #pragma unroll
        for (int i = LCH - 1; i >= 0; --i) {
            ar[i] = a; br[i] = bb; pr[i] = p;
            WKV_STEP(a, bb, p, kt[i], vt[i], w);
        }
    }
    {
        float a = Lina[idx], bb = Linb[idx], p = Linp[idx];
        #pragma unroll
        for (int i = 0; i < LCH; ++i) {
            const size_t off = base + (size_t)i * CDIM;
            const float srt = sr[off];
            const float ps = u + kt[i];
            const float q  = fmaxf(fmaxf(p, pr[i]), ps);
            const float eL = __expf(p - q);
            const float eR = __expf(pr[i] - q);
            const float eS = __expf(ps - q);
            const float num = eL * a  + eR * ar[i] + eS * vt[i];
            const float den = eL * bb + eR * br[i] + eS;
            const float zz = srt * (num / den);
            const unsigned short h = f2bf(zz);
            zh[off] = h;
            zl[off] = f2bf(zz - bf2f(h));
            WKV_STEP(a, bb, p, kt[i], vt[i], w);
        }
    }
}

// ---------------------------------------------------------------------------
// Driver. ws layout: [8 weight bf16 planes | per-chunk: k,v,sr f32; 12 state
// planes; xh,xl bf16 (aliased by zh,zl)]. Batch-chunked to fit ws_size.
// ---------------------------------------------------------------------------
extern "C" void kernel_launch(void* const* d_in, const int* in_sizes, int n_in,
                              void* d_out, int out_size, void* d_ws, size_t ws_size,
                              hipStream_t stream) {
    const float* x     = (const float*)d_in[0];
    const float* Wk    = (const float*)d_in[1];
    const float* Wv    = (const float*)d_in[2];
    const float* Wr    = (const float*)d_in[3];
    const float* Wo    = (const float*)d_in[4];
    const float* decay = (const float*)d_in[5];
    const float* first = (const float*)d_in[6];
    float* out = (float*)d_out;

    const size_t WN = (size_t)CDIM * CDIM;
    const size_t wbytes = 8 * WN * sizeof(unsigned short);
    const size_t per_b  = (size_t)TLEN * CDIM * 16 + 12ull * NCH * CDIM * 4;
    if (ws_size < wbytes + per_b) return;
    int nb = (int)((ws_size - wbytes) / per_b);
    if (nb > BSZ) nb = BSZ;

    unsigned short* wsp = (unsigned short*)d_ws;
    unsigned short* Wkh = wsp + 0 * WN; unsigned short* Wkl = wsp + 1 * WN;
    unsigned short* Wvh = wsp + 2 * WN; unsigned short* Wvl = wsp + 3 * WN;
    unsigned short* Wrh = wsp + 4 * WN; unsigned short* Wrl = wsp + 5 * WN;
    unsigned short* Woh = wsp + 6 * WN; unsigned short* Wol = wsp + 7 * WN;

    const size_t NE = (size_t)nb * TLEN * CDIM;
    const size_t NP = (size_t)nb * NCH * CDIM;
    float* fbase = (float*)(wsp + 8 * WN);
    float* kk  = fbase;
    float* vv  = kk + NE;
    float* sr  = vv + NE;
    float* Sfa = sr + NE;               float* Sfb = Sfa + NP;  float* Sfp = Sfb + NP;
    float* Sba = Sfp + NP;              float* Sbb = Sba + NP;  float* Sbp = Sbb + NP;
    float* Lina = Sbp + NP;             float* Linb = Lina + NP; float* Linp = Linb + NP;
    float* Rina = Linp + NP;            float* Rinb = Rina + NP; float* Rinp = Rinb + NP;
    unsigned short* xh = (unsigned short*)(Rinp + NP);
    unsigned short* xl = xh + NE;
    unsigned short* zh = xh;  // alias: phase3 runs after the 3 input GEMMs
    unsigned short* zl = xl;

    split_f32<<<dim3((int)(WN / 1024)), dim3(256), 0, stream>>>(Wk, Wkh, Wkl, (int)(WN / 4));
    split_f32<<<dim3((int)(WN / 1024)), dim3(256), 0, stream>>>(Wv, Wvh, Wvl, (int)(WN / 4));
    split_f32<<<dim3((int)(WN / 1024)), dim3(256), 0, stream>>>(Wr, Wrh, Wrl, (int)(WN / 4));
    split_f32<<<dim3((int)(WN / 1024)), dim3(256), 0, stream>>>(Wo, Woh, Wol, (int)(WN / 4));

    for (int b0 = 0; b0 < BSZ; b0 += nb) {
        const int curb = (BSZ - b0 < nb) ? (BSZ - b0) : nb;
        const int rows = curb * TLEN;
        const float* xc = x   + (size_t)b0 * TLEN * CDIM;
        float*       oc = out + (size_t)b0 * TLEN * CDIM;

        const int n4 = rows * CDIM / 4;
        split_f32<<<dim3(n4 / 256), dim3(256), 0, stream>>>(xc, xh, xl, n4);

        const int mtiles = rows / 256;
        const int nblk = mtiles * 4;           // BN=192: 4 ntiles
        const int mpx  = mtiles / 8;           // mtile-groups per XCD
        gemm_mfma_split<<<dim3(nblk), dim3(512), 0, stream>>>(xh, xl, Wkh, Wkl, kk, mpx, 0);
        gemm_mfma_split<<<dim3(nblk), dim3(512), 0, stream>>>(xh, xl, Wvh, Wvl, vv, mpx, 0);
        gemm_mfma_split<<<dim3(nblk), dim3(512), 0, stream>>>(xh, xl, Wrh, Wrl, sr, mpx, 1);

        wkv_phase1<<<dim3(CDIM / 256, NCH, curb), dim3(256), 0, stream>>>(
            kk, vv, decay, Sfa, Sfb, Sfp, Sba, Sbb, Sbp);
        wkv_phase2<<<dim3(CDIM / 64, curb, 2), dim3(64), 0, stream>>>(
            Sfa, Sfb, Sfp, Sba, Sbb, Sbp, decay,
            Lina, Linb, Linp, Rina, Rinb, Rinp);
        wkv_phase3<<<dim3(CDIM / 256, NCH, curb), dim3(256), 0, stream>>>(
            kk, vv, sr, Lina, Linb, Linp, Rina, Rinb, Rinp, decay, first, zh, zl);

        gemm_mfma_split<<<dim3(nblk), dim3(512), 0, stream>>>(zh, zl, Woh, Wol, oc, mpx, 0);
    }
}